// Round 9
// baseline (354.536 us; speedup 1.0000x reference)
//
#include <hip/hip_runtime.h>
#include <cmath>

static constexpr float NEG_SLOPE = 0.2f;
static constexpr int BCAP = 262144;      // records per bucket (mean 212.5k, +115 sigma)
static constexpr int CHUNK = 6144;       // edges per block in bucket_kernel
static constexpr int LCAP = 1500;        // LDS bin capacity (mean 768, +28 sigma)

typedef __attribute__((ext_vector_type(8))) short short8;   // 8 bf16 = 4 VGPR
typedef __attribute__((ext_vector_type(4))) float f32x4;

// fp32 -> bf16 round-to-nearest-even
__device__ __forceinline__ short f2bf(float f) {
  unsigned u = __float_as_uint(f);
  unsigned r = (u + 0x7FFFu + ((u >> 16) & 1u)) >> 16;
  return (short)r;
}
__device__ __forceinline__ float bf2f(short v) {
  return __uint_as_float(((unsigned)(unsigned short)v) << 16);
}

// W[K][C] (fp32) -> Wt[C][K] (bf16)
__global__ void transpose_cvt(const float* __restrict__ W, short* __restrict__ Wt,
                              int K, int C) {
  int idx = blockIdx.x * blockDim.x + threadIdx.x;
  if (idx >= K * C) return;
  int k = idx / C, c = idx % C;
  Wt[c * K + k] = f2bf(W[idx]);
}

// ---- bf16-MFMA GEMM: h[M,BN] = A[M,KTOT] * W[KTOT,BN], W transposed bf16.
// A is fp32 (A_BF16=false) or bf16 (true). h written BF16. Fused s/d dots (fp32).
template<int BN, int KTOT, bool A_BF16>
__launch_bounds__(256)
__global__ void gemm_mfma(const void* __restrict__ Av, const short* __restrict__ Bt,
                          const float* __restrict__ a_s, const float* __restrict__ a_d,
                          short* __restrict__ h, float* __restrict__ s,
                          float* __restrict__ d, int M) {
  constexpr int BM = 64, BK = 64;
  constexpr int NFRAG = BN / 16;
  __shared__ char smem[8192 + BN * 128];          // A: 64x64 bf16, Bt: BNx64 bf16
  char* As = smem;
  char* Bs = smem + 8192;

  const int tid = threadIdx.x;
  const int row0 = blockIdx.x * BM;
  const int lane = tid & 63;
  const int w = tid >> 6;
  const int r15 = lane & 15, g = lane >> 4;

  f32x4 acc[NFRAG];
  #pragma unroll
  for (int j = 0; j < NFRAG; ++j) acc[j] = (f32x4)(0.f);

  for (int k0 = 0; k0 < KTOT; k0 += BK) {
    // ---- stage A tile (64 rows x 64 k)
    {
      int row = tid >> 2, q = tid & 3;
      int gr = row0 + row;
      short8 s0, s1;
      if (A_BF16) {
        const short* A = (const short*)Av;
        if (gr < M) {
          const short* ap = A + (size_t)gr * KTOT + k0 + q * 16;
          s0 = *reinterpret_cast<const short8*>(ap);
          s1 = *reinterpret_cast<const short8*>(ap + 8);
        } else {
          #pragma unroll
          for (int t = 0; t < 8; ++t) { s0[t] = 0; s1[t] = 0; }
        }
      } else {
        const float* A = (const float*)Av;
        float vv[16];
        if (gr < M) {
          const float* ap = A + (size_t)gr * KTOT + k0 + q * 16;
          #pragma unroll
          for (int t = 0; t < 4; ++t) {
            float4 v = *reinterpret_cast<const float4*>(ap + 4 * t);
            vv[4*t] = v.x; vv[4*t+1] = v.y; vv[4*t+2] = v.z; vv[4*t+3] = v.w;
          }
        } else {
          #pragma unroll
          for (int t = 0; t < 16; ++t) vv[t] = 0.f;
        }
        #pragma unroll
        for (int t = 0; t < 8; ++t) { s0[t] = f2bf(vv[t]); s1[t] = f2bf(vv[8+t]); }
      }
      int swz = (row & 7) << 4;
      int b0 = row * 128 + q * 32;
      *reinterpret_cast<short8*>(As + (b0 ^ swz)) = s0;
      *reinterpret_cast<short8*>(As + ((b0 + 16) ^ swz)) = s1;
    }
    // ---- stage Bt tile (BN cols x 64 k, already bf16)
    if (BN == 128) {
      int col = tid >> 1, half = tid & 1;
      const short* bp = Bt + (size_t)col * KTOT + k0 + half * 32;
      int swz = (col & 7) << 4;
      int b0 = col * 128 + half * 64;
      #pragma unroll
      for (int t = 0; t < 4; ++t) {
        short8 v = *reinterpret_cast<const short8*>(bp + 8 * t);
        *reinterpret_cast<short8*>(Bs + ((b0 + 16 * t) ^ swz)) = v;
      }
    } else {
      int col = tid >> 2, q = tid & 3;
      const short* bp = Bt + (size_t)col * KTOT + k0 + q * 16;
      int swz = (col & 7) << 4;
      int b0 = col * 128 + q * 32;
      #pragma unroll
      for (int t = 0; t < 2; ++t) {
        short8 v = *reinterpret_cast<const short8*>(bp + 8 * t);
        *reinterpret_cast<short8*>(Bs + ((b0 + 16 * t) ^ swz)) = v;
      }
    }
    __syncthreads();
    // ---- MFMA: wave w owns rows [w*16, w*16+16) x all BN cols
    #pragma unroll
    for (int kc = 0; kc < BK; kc += 32) {
      int arow = w * 16 + r15;
      short8 af = *reinterpret_cast<const short8*>(
          As + ((arow * 128 + (kc + g * 8) * 2) ^ ((r15 & 7) << 4)));
      #pragma unroll
      for (int j = 0; j < NFRAG; ++j) {
        int col = j * 16 + r15;
        short8 bf = *reinterpret_cast<const short8*>(
            Bs + ((col * 128 + (kc + g * 8) * 2) ^ ((r15 & 7) << 4)));
        acc[j] = __builtin_amdgcn_mfma_f32_16x16x32_bf16(af, bf, acc[j], 0, 0, 0);
      }
    }
    __syncthreads();
  }

  // ---- epilogue: write h (bf16) + fused s/d dots (fp32)
  float ps[4] = {0.f, 0.f, 0.f, 0.f}, pd[4] = {0.f, 0.f, 0.f, 0.f};
  #pragma unroll
  for (int j = 0; j < NFRAG; ++j) {
    float asj = a_s[j * 16 + r15], adj = a_d[j * 16 + r15];
    #pragma unroll
    for (int r = 0; r < 4; ++r) {
      ps[r] = fmaf(acc[j][r], asj, ps[r]);
      pd[r] = fmaf(acc[j][r], adj, pd[r]);
    }
  }
  #pragma unroll
  for (int off = 1; off < 16; off <<= 1) {
    #pragma unroll
    for (int r = 0; r < 4; ++r) {
      ps[r] += __shfl_xor(ps[r], off);
      pd[r] += __shfl_xor(pd[r], off);
    }
  }
  #pragma unroll
  for (int r = 0; r < 4; ++r) {
    int gr = row0 + w * 16 + g * 4 + r;
    if (gr < M) {
      #pragma unroll
      for (int j = 0; j < NFRAG; ++j)
        h[(size_t)gr * BN + j * 16 + r15] = f2bf(acc[j][r]);
      if (r15 == 0) { s[gr] = ps[r]; d[gr] = pd[r]; }
    }
  }
}

// ---------------- CSR build via one-pass LDS multisplit ----------------
// Record pack: dst = hi*128 + g*16 + lo4 where g = (dst>>4)&7 is the bucket id.
// rec = (src << 14) | (hi << 4) | lo4   (src 17b, hi 10b, lo4 4b = 31 bits)
__device__ __forceinline__ unsigned pack_rec(int si, int di) {
  return ((unsigned)si << 14) | (((unsigned)(di >> 7)) << 4) | (unsigned)(di & 15);
}
__device__ __forceinline__ int rec_dst(unsigned r, int g) {
  return (int)(((r & 0x3FFFu) >> 4) << 7) | (g << 4) | (int)(r & 15u);
}

__global__ void bucket_kernel(const int* __restrict__ ei, int E, int N, int Et,
                              int* __restrict__ bcur, unsigned* __restrict__ rec) {
  __shared__ unsigned bins[8][LCAP];
  __shared__ int lcnt[8], gbase[8];
  int tid = threadIdx.x;
  if (tid < 8) lcnt[tid] = 0;
  __syncthreads();
  int e0 = blockIdx.x * CHUNK;
  for (int t = tid; t < CHUNK; t += 256) {
    int e = e0 + t;
    if (e >= Et) break;
    int si, di;
    if (e < E) {
      si = __builtin_nontemporal_load(ei + e);
      di = __builtin_nontemporal_load(ei + E + e);
    } else { si = e - E; di = si; }
    int g = (di >> 4) & 7;
    unsigned r = pack_rec(si, di);
    int p = atomicAdd(&lcnt[g], 1);
    if (p < LCAP) bins[g][p] = r;
    else {   // never expected (28 sigma); correctness fallback
      int gp = atomicAdd(&bcur[g], 1);
      rec[(size_t)g * BCAP + gp] = r;
    }
  }
  __syncthreads();
  if (tid < 8) {
    int c = min(lcnt[tid], LCAP);
    lcnt[tid] = c;
    gbase[tid] = atomicAdd(&bcur[tid], c);
  }
  __syncthreads();
  #pragma unroll
  for (int g = 0; g < 8; ++g) {
    int cnt = lcnt[g], base = gbase[g];
    for (int t = tid; t < cnt; t += 256)
      rec[(size_t)g * BCAP + base + t] = bins[g][t];
  }
}

// blocks with blockIdx&7==g sweep bucket g only -> deg/cursor/col lines XCD-local
__global__ void hist_b(const unsigned* __restrict__ rec, const int* __restrict__ bcur,
                       int* __restrict__ deg) {
  int g = blockIdx.x & 7;
  int cnt = bcur[g];
  int idx = (blockIdx.x >> 3) * blockDim.x + threadIdx.x;
  int stride = (gridDim.x >> 3) * blockDim.x;
  for (int i = idx; i < cnt; i += stride) {
    unsigned r = __builtin_nontemporal_load(rec + (size_t)g * BCAP + i);
    atomicAdd(deg + rec_dst(r, g), 1);
  }
}

__global__ void scatter_b(const unsigned* __restrict__ rec, const int* __restrict__ bcur,
                          int* __restrict__ cursor, int* __restrict__ col) {
  int g = blockIdx.x & 7;
  int cnt = bcur[g];
  int idx = (blockIdx.x >> 3) * blockDim.x + threadIdx.x;
  int stride = (gridDim.x >> 3) * blockDim.x;
  for (int i = idx; i < cnt; i += stride) {
    unsigned r = __builtin_nontemporal_load(rec + (size_t)g * BCAP + i);
    int pos = atomicAdd(cursor + rec_dst(r, g), 1);
    col[pos] = (int)(r >> 14);
  }
}

__global__ void scan1_kernel(const int* __restrict__ deg, int* __restrict__ excl,
                             int* __restrict__ bsum, int N) {
  __shared__ int tmp[256];
  int tid = threadIdx.x;
  int i = blockIdx.x * 256 + tid;
  int v = (i < N) ? deg[i] : 0;
  tmp[tid] = v;
  __syncthreads();
  #pragma unroll
  for (int off = 1; off < 256; off <<= 1) {
    int t = (tid >= off) ? tmp[tid - off] : 0;
    __syncthreads();
    tmp[tid] += t;
    __syncthreads();
  }
  if (i < N) excl[i] = tmp[tid] - v;
  if (tid == 255) bsum[blockIdx.x] = tmp[255];
}

__global__ void scan2_kernel(int* __restrict__ bsum, int nblk) {
  __shared__ int tmp[512];
  int tid = threadIdx.x;
  int v = (tid < nblk) ? bsum[tid] : 0;
  tmp[tid] = v;
  __syncthreads();
  #pragma unroll
  for (int off = 1; off < 512; off <<= 1) {
    int t = (tid >= off) ? tmp[tid - off] : 0;
    __syncthreads();
    tmp[tid] += t;
    __syncthreads();
  }
  if (tid < nblk) bsum[tid] = tmp[tid] - v;   // exclusive
}

__global__ void scan3_kernel(int* __restrict__ row_ptr, int* __restrict__ cursor,
                             const int* __restrict__ bsum, int N, int Et) {
  int i = blockIdx.x * blockDim.x + threadIdx.x;
  if (i < N) {
    int v = row_ptr[i] + bsum[i >> 8];
    row_ptr[i] = v;
    cursor[i] = v;
  }
  if (i == 0) row_ptr[N] = Et;
}

// ---------------- fused per-dst aggregation (one wave per dst) ----------------
// No segment-max pass (softmax shift-invariance; logits bounded by leaky_relu).
// Lane-group layout: F=128 -> 4 groups x 16 lanes; F=64 -> 8 groups x 8 lanes.
template<int F, int ACT, bool OUT_BF16>  // ACT: 0 relu, 1 sigmoid
__global__ void gat_aggregate(const int* __restrict__ row_ptr, const int* __restrict__ col,
                              const float* __restrict__ s, const float* __restrict__ d,
                              const short* __restrict__ hb, const float* __restrict__ b,
                              void* __restrict__ out, int N) {
  constexpr int GL = F / 8;          // lanes per group (16 or 8)
  constexpr int NG = 64 / GL;        // groups = edges in flight (4 or 8)
  int wv = (blockIdx.x * blockDim.x + threadIdx.x) >> 6;
  int lane = threadIdx.x & 63;
  if (wv >= N) return;
  const int start = row_ptr[wv];
  const int end   = row_ptr[wv + 1];
  const float dd = d[wv];
  const int gl = lane % GL;          // column-slot within group
  const int g  = lane / GL;          // group id

  float acc[8];
  #pragma unroll
  for (int t = 0; t < 8; ++t) acc[t] = 0.f;
  float wsum = 0.f;

  for (int c0 = start; c0 < end; c0 += 64) {
    int j = c0 + lane;
    int li = (j < end) ? col[j] : 0;
    float w = 0.f;
    if (j < end) {
      float l = s[li] + dd;
      l = (l > 0.f) ? l : NEG_SLOPE * l;
      w = __expf(l);
    }
    wsum += w;
    int nn = min(64, end - c0);
    for (int kk = 0; kk < nn; kk += NG) {
      int e = kk + g;
      float we = __shfl(w, e);
      int   se = __shfl(li, e);
      if (e < nn) {
        short8 v = *reinterpret_cast<const short8*>(hb + (size_t)se * F + gl * 8);
        #pragma unroll
        for (int t = 0; t < 8; ++t) acc[t] = fmaf(we, bf2f(v[t]), acc[t]);
      }
    }
  }
  // full-wave wsum reduce
  #pragma unroll
  for (int off = 32; off; off >>= 1) wsum += __shfl_xor(wsum, off);
  // cross-group acc reduce (groups hold partials for the same column slice)
  #pragma unroll
  for (int off = GL; off < 64; off <<= 1) {
    #pragma unroll
    for (int t = 0; t < 8; ++t) acc[t] += __shfl_xor(acc[t], off);
  }
  float inv = 1.f / (wsum + 1e-16f);

  if (F == 128) {
    int c = gl * 8 + g * 2;
    float o0 = fmaf(acc[g*2],     inv, b[c]);
    float o1 = fmaf(acc[g*2 + 1], inv, b[c + 1]);
    if (ACT == 0) { o0 = fmaxf(o0, 0.f); o1 = fmaxf(o1, 0.f); }
    else { o0 = 1.f / (1.f + __expf(-o0)); o1 = 1.f / (1.f + __expf(-o1)); }
    if (OUT_BF16) {
      unsigned p = ((unsigned)(unsigned short)f2bf(o1) << 16) | (unsigned short)f2bf(o0);
      reinterpret_cast<unsigned*>(out)[((size_t)wv * F + c) >> 1] = p;
    } else {
      reinterpret_cast<float2*>(out)[((size_t)wv * F + c) >> 1] = make_float2(o0, o1);
    }
  } else {
    int c = gl * 8 + g;
    float o0 = fmaf(acc[g], inv, b[c]);
    if (ACT == 0) o0 = fmaxf(o0, 0.f);
    else o0 = 1.f / (1.f + __expf(-o0));
    if (OUT_BF16) reinterpret_cast<short*>(out)[(size_t)wv * F + c] = f2bf(o0);
    else          reinterpret_cast<float*>(out)[(size_t)wv * F + c] = o0;
  }
}

extern "C" void kernel_launch(void* const* d_in, const int* in_sizes, int n_in,
                              void* d_out, int out_size, void* d_ws, size_t ws_size,
                              hipStream_t stream) {
  const int*   ei     = (const int*)d_in[0];
  const float* embed  = (const float*)d_in[1];
  const float* W1     = (const float*)d_in[2];
  const float* a_src1 = (const float*)d_in[3];
  const float* a_dst1 = (const float*)d_in[4];
  const float* b1     = (const float*)d_in[5];
  const float* W2     = (const float*)d_in[6];
  const float* a_src2 = (const float*)d_in[7];
  const float* a_dst2 = (const float*)d_in[8];
  const float* b2     = (const float*)d_in[9];

  const int E  = in_sizes[0] / 2;
  const int H  = in_sizes[3];          // 128
  const int C  = in_sizes[2] / H;      // 256
  const int N  = in_sizes[1] / C;      // 100000
  const int Et = E + N;

  auto al16 = [](size_t x) { return (x + 15) & ~(size_t)15; };
  char* p = (char*)d_ws;
  short* hb = (short*)p;      p += al16((size_t)N * 128 * 2);
  short* xb = (short*)p;      p += al16((size_t)N * 128 * 2);
  float* sv = (float*)p;      p += al16((size_t)N * 4);
  float* dv = (float*)p;      p += al16((size_t)N * 4);
  int* row_ptr = (int*)p;     p += al16((size_t)(N + 1) * 4);
  int* cursor  = (int*)p;     p += al16((size_t)N * 4);
  int* bsum    = (int*)p;     p += al16(512 * 4);
  int* col     = (int*)p;     p += al16((size_t)Et * 4);
  int* bcur    = (int*)p;     p += al16(8 * 4);
  unsigned* rec = (unsigned*)p; p += al16((size_t)8 * BCAP * 4);
  short* Wt1   = (short*)p;   p += al16((size_t)C * H * 2);
  short* Wt2   = (short*)p;

  dim3 blk(256);
  const int nblk = (N + 255) / 256;

  // ---------------- weight transpose+cvt (tiny) ----------------
  transpose_cvt<<<dim3((C*H + 255)/256), blk, 0, stream>>>(W1, Wt1, C, H);
  transpose_cvt<<<dim3((H*64 + 255)/256), blk, 0, stream>>>(W2, Wt2, H, 64);

  // ---------------- CSR build: multisplit -> hist -> scan -> scatter --------
  hipMemsetAsync(row_ptr, 0, (size_t)N * sizeof(int), stream);  // deg
  hipMemsetAsync(bcur, 0, 8 * sizeof(int), stream);
  bucket_kernel<<<dim3((Et + CHUNK - 1)/CHUNK), blk, 0, stream>>>(ei, E, N, Et, bcur, rec);
  hist_b<<<dim3(1024), blk, 0, stream>>>(rec, bcur, row_ptr);
  scan1_kernel<<<dim3(nblk), blk, 0, stream>>>(row_ptr, row_ptr, bsum, N);
  scan2_kernel<<<dim3(1), dim3(512), 0, stream>>>(bsum, nblk);
  scan3_kernel<<<dim3(nblk), blk, 0, stream>>>(row_ptr, cursor, bsum, N, Et);
  scatter_b<<<dim3(1024), blk, 0, stream>>>(rec, bcur, cursor, col);

  // ---------------- layer 1 ----------------
  gemm_mfma<128, 256, false><<<dim3((N + 63)/64), blk, 0, stream>>>(embed, Wt1, a_src1,
                                                                    a_dst1, hb, sv, dv, N);
  gat_aggregate<128,0,true><<<dim3((N + 3)/4), blk, 0, stream>>>(row_ptr, col, sv, dv,
                                                                 hb, b1, xb, N);

  // ---------------- layer 2 ----------------
  gemm_mfma<64, 128, true><<<dim3((N + 63)/64), blk, 0, stream>>>(xb, Wt2, a_src2,
                                                                  a_dst2, hb, sv, dv, N);
  gat_aggregate<64,1,false><<<dim3((N + 3)/4), blk, 0, stream>>>(row_ptr, col, sv, dv,
                                                                 hb, b2, d_out, N);
}